// Round 1
// baseline (356.707 us; speedup 1.0000x reference)
//
#include <hip/hip_runtime.h>
#include <hip/hip_bf16.h>
#include <math.h>

#define NN 25000
#define NE 250000
#define DD 64
#define HH 4
#define NGROUP (NE / 16)   // 15625 16-edge groups

typedef __attribute__((ext_vector_type(8))) short bf16x8;
typedef __attribute__((ext_vector_type(4))) float f32x4;

#define WT_LD 136   // 128 + 8 pad (shorts) -> 272B row stride

__device__ __forceinline__ float softplus_f(float x) {
    return fmaxf(x, 0.0f) + __logf(1.0f + __expf(-fabsf(x)));
}

__device__ __forceinline__ unsigned short f2bf(float f) {
    __hip_bfloat16 h = __float2bfloat16(f);
    unsigned short u;
    __builtin_memcpy(&u, &h, 2);
    return u;
}

__device__ __forceinline__ float bf2f(unsigned short u) {
    return __uint_as_float(((unsigned int)u) << 16);
}

// Load 8 consecutive floats, split each into bf16 hi + bf16 lo (compensated).
__device__ __forceinline__ void load8(const float* p, bf16x8& hi, bf16x8& lo) {
    float4 a = *(const float4*)p;
    float4 b = *(const float4*)(p + 4);
    float v[8] = {a.x, a.y, a.z, a.w, b.x, b.y, b.z, b.w};
#pragma unroll
    for (int i = 0; i < 8; ++i) {
        unsigned short h = f2bf(v[i]);
        hi[i] = (short)h;
        lo[i] = (short)f2bf(v[i] - bf2f(h));
    }
}

// One wave = 16 edges, mfma_f32_16x16x32_bf16, A gathered straight into lanes,
// W^T bf16 in LDS (one copy shared by the block's waves).
// OCCUPANCY NOTE (r0 this session): LDS=71680B -> exactly 2 blocks/CU. With
// 512-thr blocks that hard-caps 16 waves/CU (50%); measured 35%. Same LDS at
// 1024 thr/block -> 2 blocks x 16 waves = 32 waves/CU cap. VGPR=64 -> 8
// waves/SIMD fine.
__global__ __launch_bounds__(1024, 2)
void k_edge(const float* __restrict__ x, const float* __restrict__ ea,
            const float* __restrict__ W, const float* __restrict__ att,
            const float* __restrict__ bn_g, const float* __restrict__ bn_b,
            const float* __restrict__ bn_m, const float* __restrict__ bn_v,
            const int* __restrict__ eidx,
            unsigned short* __restrict__ outj,
            float* __restrict__ expa)
{
    __shared__ unsigned short Wsh[256 * WT_LD];  // W^T bf16 [n][k], padded
    __shared__ float attI[256], attJ[256];

    const int tid = threadIdx.x;
    const int lane = tid & 63;
    const int q = lane >> 4;      // quad 0..3
    const int r = lane & 15;

    // Stage W^T (coalesced read of W[k*256+n], n fast-varying).
    for (int idx = tid; idx < 32768; idx += 1024) {
        int k = idx >> 8, n = idx & 255;
        Wsh[n * WT_LD + k] = f2bf(W[idx]);
    }
    if (tid < 256) {
        int c = tid;
        attI[c] = att[(c >> 6) * 128 + (c & 63)];
        attJ[c] = att[(c >> 6) * 128 + 64 + (c & 63)];
    }
    float bnsc[HH], bnsh[HH];
#pragma unroll
    for (int t = 0; t < HH; ++t) {
        float inv = rsqrtf(bn_v[t] + 1e-5f);
        bnsc[t] = bn_g[t] * inv;
        bnsh[t] = bn_b[t] - bn_m[t] * bn_g[t] * inv;
    }
    __syncthreads();

    const int gw = blockIdx.x * 16 + (tid >> 6);
    const int nw = gridDim.x * 16;

    for (int g = gw; g < NGROUP; g += nw) {
        const int e0 = g * 16;
        const int ei = eidx[e0 + r];
        const int ej = eidx[NE + e0 + r];
        const float* xi = x + (size_t)ei * DD;
        const float* xj = x + (size_t)ej * DD;
        const float* ev = ea + (size_t)(e0 + r) * DD;

        bf16x8 Ahi[6], Alo[6];  // 0,1: x_i k-tiles; 2,3: x_j; 4,5: ea
        load8(xi + q * 8,      Ahi[0], Alo[0]);
        load8(xi + 32 + q * 8, Ahi[1], Alo[1]);
        load8(xj + q * 8,      Ahi[2], Alo[2]);
        load8(xj + 32 + q * 8, Ahi[3], Alo[3]);
        load8(ev + q * 8,      Ahi[4], Alo[4]);
        load8(ev + 32 + q * 8, Ahi[5], Alo[5]);

        float lg[4][4];  // [reg][head]
#pragma unroll
        for (int a = 0; a < 4; ++a)
#pragma unroll
            for (int b = 0; b < 4; ++b) lg[a][b] = 0.f;

        // ---- fused MFMA + epilogue: iteration nt handles col-tiles
        // {nt+4h | h=0..3} (one col per head per lane -> one ushort4 store) ----
#pragma unroll
        for (int nt = 0; nt < 4; ++nt) {
            f32x4 ai[4], aj[4];
#pragma unroll
            for (int h = 0; h < 4; ++h) {
                ai[h] = (f32x4){0.f, 0.f, 0.f, 0.f};
                aj[h] = (f32x4){0.f, 0.f, 0.f, 0.f};
            }
#pragma unroll
            for (int h = 0; h < 4; ++h) {
                const unsigned short* bp = &Wsh[((nt + 4 * h) * 16 + r) * WT_LD + q * 8];
#pragma unroll
                for (int kt = 0; kt < 4; ++kt) {
                    bf16x8 bf = *(const bf16x8*)(bp + kt * 32);
                    const int fi = (kt < 2) ? kt : kt + 2;  // x_i, x_i, ea, ea
                    const int fj = kt + 2;                  // x_j, x_j, ea, ea
                    ai[h] = __builtin_amdgcn_mfma_f32_16x16x32_bf16(Ahi[fi], bf, ai[h], 0, 0, 0);
                    ai[h] = __builtin_amdgcn_mfma_f32_16x16x32_bf16(Alo[fi], bf, ai[h], 0, 0, 0);
                    aj[h] = __builtin_amdgcn_mfma_f32_16x16x32_bf16(Ahi[fj], bf, aj[h], 0, 0, 0);
                    aj[h] = __builtin_amdgcn_mfma_f32_16x16x32_bf16(Alo[fj], bf, aj[h], 0, 0, 0);
                }
            }
            // consume: softplus, att partials, pack+store outj (acc dies here)
            const int dbase = nt * 16 + r;   // dim index d for this lane
#pragma unroll
            for (int reg = 0; reg < 4; ++reg) {
                ushort4 pk;
                unsigned short* pkp = (unsigned short*)&pk;
#pragma unroll
                for (int h = 0; h < 4; ++h) {
                    const int c = dbase + 64 * h;
                    float spi = softplus_f(ai[h][reg]);
                    float spj = softplus_f(aj[h][reg]);
                    lg[reg][h] += spi * attI[c] + spj * attJ[c];
                    pkp[h] = f2bf(spj);
                }
                const unsigned e = (unsigned)(e0 + q * 4 + reg);
                *(ushort4*)&outj[e * 256 + dbase * 4] = pk;
            }
        }

        // ---- logit reduce + BN + exp ----
#pragma unroll
        for (int off = 1; off < 16; off <<= 1) {
#pragma unroll
            for (int a = 0; a < 4; ++a)
#pragma unroll
                for (int b = 0; b < 4; ++b)
                    lg[a][b] += __shfl_xor(lg[a][b], off, 64);
        }
        float exv[4][4];
#pragma unroll
        for (int reg = 0; reg < 4; ++reg)
#pragma unroll
            for (int h = 0; h < 4; ++h)
                exv[reg][h] = __expf(softplus_f(fmaf(lg[reg][h], bnsc[h], bnsh[h])));

        if (r < 4) {  // lane r handles head r for its quad's 4 edges
#pragma unroll
            for (int reg = 0; reg < 4; ++reg) {
                const int e = e0 + q * 4 + reg;
                expa[e * 4 + r] = exv[reg][r];
            }
        }
    }
}

// ---- CSR build: counting sort of edges by target node i ----
__global__ __launch_bounds__(256)
void k_hist(const int* __restrict__ eidx, int* __restrict__ deg)
{
    const int e = blockIdx.x * 256 + threadIdx.x;
    if (e < NE) atomicAdd(&deg[eidx[e]], 1);
}

// Single-block exclusive scan of deg[NN] -> offs[NN+1]. Each thread owns 25
// consecutive nodes; Hillis-Steele over the 1024 per-thread sums.
__global__ __launch_bounds__(1024)
void k_scan(const int* __restrict__ deg, int* __restrict__ offs)
{
    __shared__ int sh[1024];
    const int t = threadIdx.x;
    const int base = t * 25;
    int s = 0;
#pragma unroll
    for (int k = 0; k < 25; ++k) {
        int idx = base + k;
        if (idx < NN) s += deg[idx];
    }
    sh[t] = s;
    __syncthreads();
    for (int off = 1; off < 1024; off <<= 1) {
        int v = (t >= off) ? sh[t - off] : 0;
        __syncthreads();
        sh[t] += v;
        __syncthreads();
    }
    int run = sh[t] - s;   // exclusive prefix for this thread's chunk
#pragma unroll
    for (int k = 0; k < 25; ++k) {
        int idx = base + k;
        if (idx < NN) {
            offs[idx] = run;
            run += deg[idx];
        } else if (idx == NN) {
            offs[NN] = run;   // == NE
        }
    }
}

__global__ __launch_bounds__(256)
void k_fill(const int* __restrict__ eidx, const int* __restrict__ offs,
            int* __restrict__ cursor, int* __restrict__ elist)
{
    const int e = blockIdx.x * 256 + threadIdx.x;
    if (e < NE) {
        const int i = eidx[e];
        const int p = atomicAdd(&cursor[i], 1);
        elist[offs[i] + p] = e;
    }
}

// One wave per node: pass1 sums exp-alphas (denom, shuffle reduce), pass2
// gathers outj rows and accumulates the weighted mean. Zero output atomics;
// folds k_final (bias + /4) and deletes the denom buffer + big memset.
__global__ __launch_bounds__(256)
void k_aggr(const int* __restrict__ offs, const int* __restrict__ elist,
            const unsigned short* __restrict__ outj,
            const float* __restrict__ expa,
            const float* __restrict__ bias, float* __restrict__ out)
{
    const int n = blockIdx.x * 4 + (threadIdx.x >> 6);
    const int lane = threadIdx.x & 63;
    const int beg = offs[n];
    const int end = offs[n + 1];

    // pass 1: denom per head
    float4 s = make_float4(0.f, 0.f, 0.f, 0.f);
    for (int t = beg + lane; t < end; t += 64) {
        const int e = elist[t];
        float4 v = *(const float4*)&expa[e * 4];
        s.x += v.x; s.y += v.y; s.z += v.z; s.w += v.w;
    }
#pragma unroll
    for (int off = 32; off >= 1; off >>= 1) {
        s.x += __shfl_xor(s.x, off, 64);
        s.y += __shfl_xor(s.y, off, 64);
        s.z += __shfl_xor(s.z, off, 64);
        s.w += __shfl_xor(s.w, off, 64);
    }
    // 0.25 head-mean folded in; deg==0 -> inf but never used (loop empty)
    const float w0 = 0.25f / s.x, w1 = 0.25f / s.y;
    const float w2 = 0.25f / s.z, w3 = 0.25f / s.w;

    // pass 2: lane = output dim d
    float sum = 0.f;
    for (int t = beg; t < end; ++t) {
        const int e = elist[t];
        float4 ev = *(const float4*)&expa[e * 4];       // broadcast across wave
        ushort4 v = *(const ushort4*)&outj[((unsigned)e << 8) | (lane << 2)];
        sum += (ev.x * w0) * bf2f(v.x) + (ev.y * w1) * bf2f(v.y)
             + (ev.z * w2) * bf2f(v.z) + (ev.w * w3) * bf2f(v.w);
    }
    out[n * DD + lane] = sum + bias[lane];
}

extern "C" void kernel_launch(void* const* d_in, const int* in_sizes, int n_in,
                              void* d_out, int out_size, void* d_ws, size_t ws_size,
                              hipStream_t stream)
{
    (void)in_sizes; (void)n_in; (void)out_size; (void)ws_size;
    const float* x    = (const float*)d_in[0];
    const float* ea   = (const float*)d_in[1];
    const float* W    = (const float*)d_in[2];
    const float* att  = (const float*)d_in[3];
    const float* bias = (const float*)d_in[4];
    const float* bn_g = (const float*)d_in[5];
    const float* bn_b = (const float*)d_in[6];
    const float* bn_m = (const float*)d_in[7];
    const float* bn_v = (const float*)d_in[8];
    const int*   eidx = (const int*)d_in[9];
    float* out = (float*)d_out;

    // ws layout:
    //   outj bf16 [E][64][4]            128,000,000 B @ 0
    //   expa f32  [E][4]                  4,000,000 B @ 128,000,000
    //   deg  i32  [N]                       100,000 B @ 132,000,000
    //   cursor i32 [N]                      100,000 B @ 132,100,000
    //   offs i32  [N+1]                     100,004 B @ 132,200,000
    //   elist i32 [E]                     1,000,000 B @ 132,300,032
    char* ws = (char*)d_ws;
    unsigned short* outj = (unsigned short*)ws;
    float* expa  = (float*)(ws + 128000000ull);
    int*   deg    = (int*)(ws + 132000000ull);
    int*   cursor = (int*)(ws + 132100000ull);
    int*   offs   = (int*)(ws + 132200000ull);
    int*   elist  = (int*)(ws + 132300032ull);

    hipMemsetAsync(deg, 0, 200000, stream);   // deg + cursor (contiguous)

    k_hist<<<dim3((NE + 255) / 256), dim3(256), 0, stream>>>(eidx, deg);
    k_scan<<<dim3(1), dim3(1024), 0, stream>>>(deg, offs);
    k_fill<<<dim3((NE + 255) / 256), dim3(256), 0, stream>>>(eidx, offs, cursor, elist);
    k_edge<<<dim3(256), dim3(1024), 0, stream>>>(
        x, ea, W, att, bn_g, bn_b, bn_m, bn_v, eidx, outj, expa);
    k_aggr<<<dim3(NN / 4), dim3(256), 0, stream>>>(offs, elist, outj, expa, bias, out);
}